// Round 7
// baseline (264.653 us; speedup 1.0000x reference)
//
#include <hip/hip_runtime.h>
#include <math.h>

#define SEQ 2048
#define NHD 16

typedef float f32x4 __attribute__((ext_vector_type(4), may_alias));
typedef _Float16 h16x8 __attribute__((ext_vector_type(8), may_alias));
typedef _Float16 h16x4 __attribute__((ext_vector_type(4), may_alias));

// async global->LDS, 16B per lane; dst wave-uniform base (+lane*16 in HW)
__device__ __forceinline__ void gl_lds16(const void* g, void* l) {
  __builtin_amdgcn_global_load_lds(
      (const __attribute__((address_space(1))) unsigned int*)g,
      (__attribute__((address_space(3))) unsigned int*)l, 16, 0, 0);
}

// ---------------------------------------------------------------------------
// Prepass (W only now): transpose W{q,k,v,o} fp32 -> fp16 [n][k]
// ---------------------------------------------------------------------------
struct PrepArgs {
  const float* W[4];
  _Float16* T[4];
};

__global__ __launch_bounds__(256) void prep_k(PrepArgs a) {
  __shared__ float tile[64][65];
  const int t = threadIdx.x;
  const int c = t & 63, r0 = t >> 6;
  const int nb = blockIdx.x * 64, kb = blockIdx.y * 64;
  const float* __restrict__ W = a.W[blockIdx.z];
  _Float16* __restrict__ T = a.T[blockIdx.z];
#pragma unroll
  for (int i = 0; i < 16; ++i) {
    const int r = i * 4 + r0;
    tile[r][c] = W[(size_t)(kb + r) * 1024 + nb + c];
  }
  __syncthreads();
#pragma unroll
  for (int i = 0; i < 16; ++i) {
    const int n = i * 4 + r0;
    T[(size_t)(nb + n) * 1024 + kb + c] = (_Float16)tile[c][n];
  }
}

// ---------------------------------------------------------------------------
// V transpose + key'-permute (fp16 bits as u16): Vb[bh][s][64] -> Vt[bh][64][2048]
// key' = (key&15)*4 + (key>>4) within each 64-key block
// ---------------------------------------------------------------------------
__global__ __launch_bounds__(256) void vtrans_k(const unsigned short* __restrict__ Vb,
                                                unsigned short* __restrict__ Vt) {
  __shared__ unsigned short tile[64][65];
  const int t = threadIdx.x;
  const int c = t & 63, r0 = t >> 6;
  const int s0 = blockIdx.x * 64;
  const int bh = blockIdx.y;
#pragma unroll
  for (int i = 0; i < 16; ++i) {
    const int r = i * 4 + r0;
    tile[r][c] = Vb[((size_t)bh * SEQ + s0 + r) * 64 + c];
  }
  __syncthreads();
#pragma unroll
  for (int i = 0; i < 16; ++i) {
    const int d = i * 4 + r0;
    const int sp = ((c & 15) * 4) + (c >> 4);
    Vt[((size_t)bh * 64 + d) * SEQ + s0 + sp] = tile[c][d];
  }
}

// ---------------------------------------------------------------------------
// QKV GEMM: C = f16(A_f32[M x 1024]) @ Bt^T + bias, head-split fp16 out.
// Tile 128x128, BK=32, 4 waves (2x2), 4x4 16x16 tiles/wave.
// A: fp32 loaded + converted inline (round-2-proven slot map);
// B: gl_lds16 direct-to-LDS frag order. LDS: A[0,8K) B[8K,16K).
// ---------------------------------------------------------------------------
struct QKVArgs {
  const float* Af[3];
  const _Float16* Bt[3];
  const float* bias[3];
  _Float16* C[3];
};

__global__ __launch_bounds__(256, 4) void gemm_qkv_k(QKVArgs a) {
  __shared__ char smem[16384];
  h16x8* lds8 = (h16x8*)smem;
  const int z = blockIdx.z;
  const float* __restrict__ Af = a.Af[z];
  const _Float16* __restrict__ Bt = a.Bt[z];
  const float* __restrict__ bias = a.bias[z];
  _Float16* __restrict__ C = a.C[z];

  const int t = threadIdx.x;
  const int l = t & 63, w = t >> 6;
  const int quad = l >> 4, l15 = l & 15;
  const int wm = w >> 1, wn = w & 1;
  const int n0 = blockIdx.x * 128, m0 = blockIdx.y * 128;

  const f32x4 z4 = {0.f, 0.f, 0.f, 0.f};
  f32x4 acc[4][4];
#pragma unroll
  for (int i = 0; i < 4; ++i)
#pragma unroll
    for (int j = 0; j < 4; ++j) acc[i][j] = z4;

  for (int k0 = 0; k0 < 1024; k0 += 32) {
    // B via async direct-to-LDS
#pragma unroll
    for (int it = 0; it < 2; ++it) {
      const int c = it * 4 + w;
      const int rr = c * 16 + l15;
      gl_lds16(Bt + (size_t)(n0 + rr) * 1024 + k0 + quad * 8, smem + 8192 + c * 1024);
    }
    // A: fp32 load + convert + ds_write (frag-order slots)
#pragma unroll
    for (int it = 0; it < 2; ++it) {
      const int row = it * 64 + (t >> 2);
      const int aq = t & 3;
      const int slot = (row >> 4) * 64 + aq * 16 + (row & 15);
      const float* src = Af + (size_t)(m0 + row) * 1024 + k0 + aq * 8;
      const f32x4 f0 = *(const f32x4*)src;
      const f32x4 f1 = *(const f32x4*)(src + 4);
      const float fs[8] = {f0.x, f0.y, f0.z, f0.w, f1.x, f1.y, f1.z, f1.w};
      h16x8 hv;
#pragma unroll
      for (int j = 0; j < 8; ++j) hv[j] = (_Float16)fs[j];
      lds8[slot] = hv;
    }
    __syncthreads();
    h16x8 af[4], bf[4];
#pragma unroll
    for (int i = 0; i < 4; ++i) {
      af[i] = lds8[(wm * 4 + i) * 64 + l];
      bf[i] = lds8[512 + (wn * 4 + i) * 64 + l];
    }
#pragma unroll
    for (int i = 0; i < 4; ++i)
#pragma unroll
      for (int j = 0; j < 4; ++j)
        acc[i][j] = __builtin_amdgcn_mfma_f32_16x16x32_f16(af[i], bf[j], acc[i][j], 0, 0, 0);
    __syncthreads();
  }
#pragma unroll
  for (int i = 0; i < 4; ++i)
#pragma unroll
    for (int j = 0; j < 4; ++j) {
      const int col = n0 + wn * 64 + j * 16 + l15;
      const float bv = bias[col];
#pragma unroll
      for (int r = 0; r < 4; ++r) {
        const int row = m0 + wm * 64 + i * 16 + quad * 4 + r;
        const int b = row >> 11, s = row & 2047;
        const int h = col >> 6, d = col & 63;
        C[((size_t)(b * NHD + h) * SEQ + s) * 64 + d] = (_Float16)(acc[i][j][r] + bv);
      }
    }
}

// ---------------------------------------------------------------------------
// Output GEMM with fused split-K combine + normalization:
//   Cf = relu( [ (Op0+Op1) * inv_l(token,head) ] @ Wo_t^T + bias )
// inv_l varies with head = k>>6 (NOT hoistable to epilogue) -> applied in
// A-staging (head = k0>>6 is wave-uniform). Per-block LDS table of
// 1/(l0+l1) for 128 rows x 16 heads. LDS: A[0,8K) B[8K,16K) inv[16K,24K).
// ---------------------------------------------------------------------------
__global__ __launch_bounds__(256, 4) void gemm_o_k(
    const _Float16* __restrict__ Op0, const _Float16* __restrict__ Op1,
    const float* __restrict__ Lp, const _Float16* __restrict__ Bt,
    const float* __restrict__ bias, float* __restrict__ Cf) {
  __shared__ char smem[24576];
  h16x8* lds8 = (h16x8*)smem;
  float* inv_lds = (float*)(smem + 16384);  // [row_local][head]
  const int t = threadIdx.x;
  const int l = t & 63, w = t >> 6;
  const int quad = l >> 4, l15 = l & 15;
  const int wm = w >> 1, wn = w & 1;
  const int n0 = blockIdx.x * 128, m0 = blockIdx.y * 128;

  // precompute inv_l for this block's 128 rows x 16 heads
#pragma unroll
  for (int e = t; e < 2048; e += 256) {
    const int rl = e >> 4, hh = e & 15;
    const int m = m0 + rl;
    const int b = m >> 11, s = m & 2047;
    const size_t li = (size_t)(b * NHD + hh) * 2048 + s;
    inv_lds[e] = 1.f / (Lp[li] + Lp[65536 + li]);
  }
  __syncthreads();

  const f32x4 z4 = {0.f, 0.f, 0.f, 0.f};
  f32x4 acc[4][4];
#pragma unroll
  for (int i = 0; i < 4; ++i)
#pragma unroll
    for (int j = 0; j < 4; ++j) acc[i][j] = z4;

  for (int k0 = 0; k0 < 1024; k0 += 32) {
#pragma unroll
    for (int it = 0; it < 2; ++it) {
      const int c = it * 4 + w;
      const int rr = c * 16 + l15;
      gl_lds16(Bt + (size_t)(n0 + rr) * 1024 + k0 + quad * 8, smem + 8192 + c * 1024);
    }
    // A: (Op0+Op1) * inv_l, staged manually
    const int head = k0 >> 6;  // aq*8 <= 24 < 64-k0%64 slack -> uniform
#pragma unroll
    for (int it = 0; it < 2; ++it) {
      const int row = it * 64 + (t >> 2);
      const int aq = t & 3;
      const int slot = (row >> 4) * 64 + aq * 16 + (row & 15);
      const size_t off = (size_t)(m0 + row) * 1024 + k0 + aq * 8;
      const h16x8 a0 = *(const h16x8*)(Op0 + off);
      const h16x8 a1 = *(const h16x8*)(Op1 + off);
      const float inv = inv_lds[row * 16 + head];
      h16x8 hv;
#pragma unroll
      for (int j = 0; j < 8; ++j)
        hv[j] = (_Float16)(((float)a0[j] + (float)a1[j]) * inv);
      lds8[slot] = hv;
    }
    __syncthreads();
    h16x8 af[4], bf[4];
#pragma unroll
    for (int i = 0; i < 4; ++i) {
      af[i] = lds8[(wm * 4 + i) * 64 + l];
      bf[i] = lds8[512 + (wn * 4 + i) * 64 + l];
    }
#pragma unroll
    for (int i = 0; i < 4; ++i)
#pragma unroll
      for (int j = 0; j < 4; ++j)
        acc[i][j] = __builtin_amdgcn_mfma_f32_16x16x32_f16(af[i], bf[j], acc[i][j], 0, 0, 0);
    __syncthreads();
  }
#pragma unroll
  for (int i = 0; i < 4; ++i)
#pragma unroll
    for (int j = 0; j < 4; ++j) {
      const int col = n0 + wn * 64 + j * 16 + l15;
      const float bv = bias[col];
#pragma unroll
      for (int r = 0; r < 4; ++r) {
        const int row = m0 + wm * 64 + i * 16 + quad * 4 + r;
        Cf[(size_t)row * 1024 + col] = fmaxf(acc[i][j][r] + bv, 0.f);
      }
    }
}

// ---------------------------------------------------------------------------
// Flash attention, split-K over 2 key halves (unchanged from round 6).
// 4 waves; 128 Q rows/block (32/wave, mi=2), 64-key tiles.
// Partials LINEAR (no softmax max): O_unnorm fp16 + l fp32.
// LDS: K[0,8K) V[8K,16K) P[16K,+8*2304) = 34816 B -> 4 blocks/CU.
// ---------------------------------------------------------------------------
__global__ __launch_bounds__(256, 4) void attn_k(
    const _Float16* __restrict__ Qf, const _Float16* __restrict__ Kf,
    const _Float16* __restrict__ Vtp,
    _Float16* __restrict__ Op0, _Float16* __restrict__ Op1,
    float* __restrict__ Lp) {
  __shared__ char smem[34816];
  h16x8* lds8 = (h16x8*)smem;
  const int t = threadIdx.x;
  const int l = t & 63, w = t >> 6;
  const int quad = l >> 4, l15 = l & 15;
  const int q0 = blockIdx.x * 128;
  const int bh = blockIdx.y;
  const int kz = blockIdx.z;
  const int b = bh >> 4, h = bh & 15;

  const _Float16* Kb = Kf + (size_t)bh * SEQ * 64;
  const _Float16* Vtb = Vtp + (size_t)bh * 64 * SEQ;

  h16x8 qf[2][2];
#pragma unroll
  for (int mi = 0; mi < 2; ++mi) {
    const size_t qb = ((size_t)bh * SEQ + q0 + w * 32 + mi * 16 + l15) * 64;
#pragma unroll
    for (int ks = 0; ks < 2; ++ks)
      qf[mi][ks] = *(const h16x8*)&Qf[qb + ks * 32 + quad * 8];
  }
  const f32x4 z4 = {0.f, 0.f, 0.f, 0.f};
  f32x4 oacc[2][4], lacc[2];
#pragma unroll
  for (int mi = 0; mi < 2; ++mi) {
    lacc[mi] = z4;
#pragma unroll
    for (int i = 0; i < 4; ++i) oacc[mi][i] = z4;
  }
  h16x8 ones;
#pragma unroll
  for (int j = 0; j < 8; ++j) ones[j] = (_Float16)1.0f;

  const int kbeg = kz * 1024;
  for (int k0 = kbeg; k0 < kbeg + 1024; k0 += 64) {
#pragma unroll
    for (int it = 0; it < 2; ++it) {
      const int c = it * 4 + w;
      const int kd = (c >> 1) * 16 + l15;
      const int off2 = (c & 1) * 32 + quad * 8;
      gl_lds16(Kb + (size_t)(k0 + kd) * 64 + off2, smem + c * 1024);
      gl_lds16(Vtb + (size_t)kd * SEQ + k0 + off2, smem + 8192 + c * 1024);
    }
    __syncthreads();

    {
      h16x8 kfr[4][2];
#pragma unroll
      for (int nt = 0; nt < 4; ++nt)
#pragma unroll
        for (int ks = 0; ks < 2; ++ks) kfr[nt][ks] = lds8[(nt * 2 + ks) * 64 + l];

#pragma unroll
      for (int mi = 0; mi < 2; ++mi) {
        f32x4 sacc[4];
#pragma unroll
        for (int nt = 0; nt < 4; ++nt) {
          f32x4 s = z4;
          s = __builtin_amdgcn_mfma_f32_16x16x32_f16(qf[mi][0], kfr[nt][0], s, 0, 0, 0);
          s = __builtin_amdgcn_mfma_f32_16x16x32_f16(qf[mi][1], kfr[nt][1], s, 0, 0, 0);
          sacc[nt] = s;
        }
        char* pb = smem + 16384 + (w * 2 + mi) * 2304;
#pragma unroll
        for (int r = 0; r < 4; ++r) {
          h16x4 pk;
#pragma unroll
          for (int nt = 0; nt < 4; ++nt)
            pk[nt] = (_Float16)__expf(sacc[nt][r] * 0.125f);
          *(h16x4*)(pb + (quad * 4 + r) * 144 + l15 * 8) = pk;
        }
      }
    }
    __asm__ __volatile__("" ::: "memory");  // same-wave DS ordering

    {
      h16x8 vfr[4][2];
#pragma unroll
      for (int nt = 0; nt < 4; ++nt)
#pragma unroll
        for (int ks = 0; ks < 2; ++ks) vfr[nt][ks] = lds8[512 + (nt * 2 + ks) * 64 + l];

#pragma unroll
      for (int mi = 0; mi < 2; ++mi) {
        char* pb = smem + 16384 + (w * 2 + mi) * 2304;
        const h16x8 pf0 = *(const h16x8*)(pb + l15 * 144 + quad * 16);
        const h16x8 pf1 = *(const h16x8*)(pb + l15 * 144 + 64 + quad * 16);
        lacc[mi] = __builtin_amdgcn_mfma_f32_16x16x32_f16(pf0, ones, lacc[mi], 0, 0, 0);
        lacc[mi] = __builtin_amdgcn_mfma_f32_16x16x32_f16(pf1, ones, lacc[mi], 0, 0, 0);
#pragma unroll
        for (int nt = 0; nt < 4; ++nt) {
          oacc[mi][nt] = __builtin_amdgcn_mfma_f32_16x16x32_f16(pf0, vfr[nt][0], oacc[mi][nt], 0, 0, 0);
          oacc[mi][nt] = __builtin_amdgcn_mfma_f32_16x16x32_f16(pf1, vfr[nt][1], oacc[mi][nt], 0, 0, 0);
        }
      }
    }
    __syncthreads();
  }

  _Float16* __restrict__ Op = kz ? Op1 : Op0;
#pragma unroll
  for (int mi = 0; mi < 2; ++mi)
#pragma unroll
    for (int nt = 0; nt < 4; ++nt)
#pragma unroll
      for (int r = 0; r < 4; ++r) {
        const size_t tok = (size_t)b * SEQ + q0 + w * 32 + mi * 16 + quad * 4 + r;
        Op[tok * 1024 + h * 64 + nt * 16 + l15] = (_Float16)oacc[mi][nt][r];
      }
  if (l15 == 0) {
#pragma unroll
    for (int mi = 0; mi < 2; ++mi)
#pragma unroll
      for (int r = 0; r < 4; ++r) {
        const int row = q0 + w * 32 + mi * 16 + quad * 4 + r;
        Lp[(size_t)kz * 65536 + bh * 2048 + row] = lacc[mi][r];
      }
  }
}

// ---------------------------------------------------------------------------
extern "C" void kernel_launch(void* const* d_in, const int* in_sizes, int n_in,
                              void* d_out, int out_size, void* d_ws, size_t ws_size,
                              hipStream_t stream) {
  const float* q = (const float*)d_in[0];
  const float* k = (const float*)d_in[1];
  const float* v = (const float*)d_in[2];
  const float* Wq = (const float*)d_in[3];
  const float* bq = (const float*)d_in[4];
  const float* Wk = (const float*)d_in[5];
  const float* bk = (const float*)d_in[6];
  const float* Wv = (const float*)d_in[7];
  const float* bv = (const float*)d_in[8];
  const float* Wo = (const float*)d_in[9];
  const float* bo = (const float*)d_in[10];

  char* W8 = (char*)d_ws;
  const size_t MB = 1024 * 1024;
  auto F = [&](size_t off) { return (_Float16*)(W8 + off); };
  // [0,8M): Wt f16 x4 | [8M,16M): Vb | [16M,24M): Vt | [24M,32M): Qf
  // [32M,40M): Kf | [40M,48M): Op0 | [48M,56M): Op1 | [56M,+512K): Lp
  _Float16* wt[4] = {F(0), F(2 * MB), F(4 * MB), F(6 * MB)};
  _Float16* Vb = F(8 * MB);
  _Float16* Vt = F(16 * MB);
  _Float16* Qf = F(24 * MB);
  _Float16* Kf = F(32 * MB);
  _Float16* Op0 = F(40 * MB);
  _Float16* Op1 = F(48 * MB);
  float* Lp = (float*)(W8 + 56 * MB);

  const dim3 blk(256);

  PrepArgs pa;
  pa.W[0] = Wq; pa.W[1] = Wk; pa.W[2] = Wv; pa.W[3] = Wo;
  pa.T[0] = wt[0]; pa.T[1] = wt[1]; pa.T[2] = wt[2]; pa.T[3] = wt[3];
  prep_k<<<dim3(16, 16, 4), blk, 0, stream>>>(pa);

  QKVArgs qa;
  qa.Af[0] = q; qa.Af[1] = k; qa.Af[2] = v;
  qa.Bt[0] = wt[0]; qa.Bt[1] = wt[1]; qa.Bt[2] = wt[2];
  qa.bias[0] = bq; qa.bias[1] = bk; qa.bias[2] = bv;
  qa.C[0] = Qf; qa.C[1] = Kf; qa.C[2] = Vb;
  gemm_qkv_k<<<dim3(8, 32, 3), blk, 0, stream>>>(qa);

  vtrans_k<<<dim3(32, 32), blk, 0, stream>>>((const unsigned short*)Vb,
                                             (unsigned short*)Vt);
  attn_k<<<dim3(16, 32, 2), blk, 0, stream>>>(Qf, Kf, Vt, Op0, Op1, Lp);
  gemm_o_k<<<dim3(8, 32), blk, 0, stream>>>(Op0, Op1, Lp, wt[3], bo, (float*)d_out);
}

// Round 8
// 261.117 us; speedup vs baseline: 1.0135x; 1.0135x over previous
//
#include <hip/hip_runtime.h>
#include <math.h>

#define SEQ 2048
#define NHD 16

typedef float f32x4 __attribute__((ext_vector_type(4), may_alias));
typedef _Float16 h16x8 __attribute__((ext_vector_type(8), may_alias));
typedef _Float16 h16x4 __attribute__((ext_vector_type(4), may_alias));

// async global->LDS, 16B per lane; dst wave-uniform base (+lane*16 in HW)
__device__ __forceinline__ void gl_lds16(const void* g, void* l) {
  __builtin_amdgcn_global_load_lds(
      (const __attribute__((address_space(1))) unsigned int*)g,
      (__attribute__((address_space(3))) unsigned int*)l, 16, 0, 0);
}

// ---------------------------------------------------------------------------
// Fused prepass: blocks [0,1024): transpose W{q,k,v,o} fp32->fp16 [n][k]
//                blocks [1024,7168): convert q,k,v fp32->fp16
// ---------------------------------------------------------------------------
struct PrepArgs {
  const float* W[4];
  _Float16* T[4];
  const float* X[3];
  _Float16* H[3];
};

__global__ __launch_bounds__(256) void prep_k(PrepArgs a) {
  __shared__ float tile[64][65];
  const int blk = blockIdx.x;
  const int t = threadIdx.x;
  if (blk < 1024) {
    const int widx = blk >> 8, tl = blk & 255;
    const int nb = (tl & 15) * 64, kb = (tl >> 4) * 64;
    const float* __restrict__ W = a.W[widx];
    _Float16* __restrict__ T = a.T[widx];
    const int c = t & 63, r0 = t >> 6;
#pragma unroll
    for (int i = 0; i < 16; ++i) {
      const int r = i * 4 + r0;
      tile[r][c] = W[(size_t)(kb + r) * 1024 + nb + c];
    }
    __syncthreads();
#pragma unroll
    for (int i = 0; i < 16; ++i) {
      const int n = i * 4 + r0;
      T[(size_t)(nb + n) * 1024 + kb + c] = (_Float16)tile[c][n];
    }
  } else {
    const int b2 = blk - 1024;
    const int z = b2 >> 11, bx = b2 & 2047;
    const float* __restrict__ X = a.X[z];
    _Float16* __restrict__ H = a.H[z];
    const size_t i = ((size_t)bx * 256 + t) * 8;
    const f32x4 f0 = *(const f32x4*)(X + i);
    const f32x4 f1 = *(const f32x4*)(X + i + 4);
    const float fs[8] = {f0.x, f0.y, f0.z, f0.w, f1.x, f1.y, f1.z, f1.w};
    h16x8 o;
#pragma unroll
    for (int j = 0; j < 8; ++j) o[j] = (_Float16)fs[j];
    *(h16x8*)(H + i) = o;
  }
}

// ---------------------------------------------------------------------------
// V transpose + key'-permute (fp16 bits as u16): Vb[bh][s][64] -> Vt[bh][64][2048]
// key' = (key&15)*4 + (key>>4) within each 64-key block
// ---------------------------------------------------------------------------
__global__ __launch_bounds__(256) void vtrans_k(const unsigned short* __restrict__ Vb,
                                                unsigned short* __restrict__ Vt) {
  __shared__ unsigned short tile[64][65];
  const int t = threadIdx.x;
  const int c = t & 63, r0 = t >> 6;
  const int s0 = blockIdx.x * 64;
  const int bh = blockIdx.y;
#pragma unroll
  for (int i = 0; i < 16; ++i) {
    const int r = i * 4 + r0;
    tile[r][c] = Vb[((size_t)bh * SEQ + s0 + r) * 64 + c];
  }
  __syncthreads();
#pragma unroll
  for (int i = 0; i < 16; ++i) {
    const int d = i * 4 + r0;
    const int sp = ((c & 15) * 4) + (c >> 4);
    Vt[((size_t)bh * 64 + d) * SEQ + s0 + sp] = tile[c][d];
  }
}

// ---------------------------------------------------------------------------
// fp16 MFMA GEMM: C = A[M x 1024] @ Bt^T + bias, head-split fp16 output.
// Tile 128x128, BK=32, 4 waves (2x2), 4x4 16x16 tiles/wave, 16 MFMA/k-step.
// LDS: A[0,8K) B[8K,16K), staged via global_load_lds dwordx4 in frag order.
// (round-4/5 proven config: presplit fp16 A, dual gl_lds16, 4 blocks/CU)
// ---------------------------------------------------------------------------
struct QKVArgs {
  const _Float16* A[3];
  const _Float16* Bt[3];
  const float* bias[3];
  _Float16* C[3];
};

__global__ __launch_bounds__(256, 4) void gemm_qkv_k(QKVArgs a) {
  __shared__ char smem[16384];
  h16x8* lds8 = (h16x8*)smem;
  const int z = blockIdx.z;
  const _Float16* __restrict__ A = a.A[z];
  const _Float16* __restrict__ Bt = a.Bt[z];
  const float* __restrict__ bias = a.bias[z];
  _Float16* __restrict__ C = a.C[z];

  const int t = threadIdx.x;
  const int l = t & 63, w = t >> 6;
  const int quad = l >> 4, l15 = l & 15;
  const int wm = w >> 1, wn = w & 1;
  const int n0 = blockIdx.x * 128, m0 = blockIdx.y * 128;

  const f32x4 z4 = {0.f, 0.f, 0.f, 0.f};
  f32x4 acc[4][4];
#pragma unroll
  for (int i = 0; i < 4; ++i)
#pragma unroll
    for (int j = 0; j < 4; ++j) acc[i][j] = z4;

  for (int k0 = 0; k0 < 1024; k0 += 32) {
#pragma unroll
    for (int it = 0; it < 2; ++it) {
      const int c = it * 4 + w;
      const int rr = c * 16 + l15;
      gl_lds16(A + (size_t)(m0 + rr) * 1024 + k0 + quad * 8, smem + c * 1024);
      gl_lds16(Bt + (size_t)(n0 + rr) * 1024 + k0 + quad * 8, smem + 8192 + c * 1024);
    }
    __syncthreads();
    h16x8 af[4], bf[4];
#pragma unroll
    for (int i = 0; i < 4; ++i) {
      af[i] = lds8[(wm * 4 + i) * 64 + l];
      bf[i] = lds8[512 + (wn * 4 + i) * 64 + l];
    }
#pragma unroll
    for (int i = 0; i < 4; ++i)
#pragma unroll
      for (int j = 0; j < 4; ++j)
        acc[i][j] = __builtin_amdgcn_mfma_f32_16x16x32_f16(af[i], bf[j], acc[i][j], 0, 0, 0);
    __syncthreads();
  }
#pragma unroll
  for (int i = 0; i < 4; ++i)
#pragma unroll
    for (int j = 0; j < 4; ++j) {
      const int col = n0 + wn * 64 + j * 16 + l15;
      const float bv = bias[col];
#pragma unroll
      for (int r = 0; r < 4; ++r) {
        const int row = m0 + wm * 64 + i * 16 + quad * 4 + r;
        const int b = row >> 11, s = row & 2047;
        const int h = col >> 6, d = col & 63;
        C[((size_t)(b * NHD + h) * SEQ + s) * 64 + d] = (_Float16)(acc[i][j][r] + bv);
      }
    }
}

// ---------------------------------------------------------------------------
// Output GEMM with fused split-K combine + normalization:
//   Cf = relu( [ (Op0+Op1) * inv_l(token,head) ] @ Wo_t^T + bias )
// inv_l applied during A-staging (head = k0>>6 wave-uniform); per-block LDS
// table 1/(l0+l1) for 128 rows x 16 heads.
// A ds_write slots XOR-swizzled ((row&15)^(2*aq)) -> <=2-way (free);
// frag readers apply matching l15^(2*quad) permutation.
// LDS: A[0,8K) B[8K,16K) inv[16K,24K).
// ---------------------------------------------------------------------------
__global__ __launch_bounds__(256, 4) void gemm_o_k(
    const _Float16* __restrict__ Op0, const _Float16* __restrict__ Op1,
    const float* __restrict__ Lp, const _Float16* __restrict__ Bt,
    const float* __restrict__ bias, float* __restrict__ Cf) {
  __shared__ char smem[24576];
  h16x8* lds8 = (h16x8*)smem;
  float* inv_lds = (float*)(smem + 16384);  // [row_local][head]
  const int t = threadIdx.x;
  const int l = t & 63, w = t >> 6;
  const int quad = l >> 4, l15 = l & 15;
  const int wm = w >> 1, wn = w & 1;
  const int n0 = blockIdx.x * 128, m0 = blockIdx.y * 128;

  // precompute inv_l for this block's 128 rows x 16 heads
#pragma unroll
  for (int e = t; e < 2048; e += 256) {
    const int rl = e >> 4, hh = e & 15;
    const int m = m0 + rl;
    const int b = m >> 11, s = m & 2047;
    const size_t li = (size_t)(b * NHD + hh) * 2048 + s;
    inv_lds[e] = 1.f / (Lp[li] + Lp[65536 + li]);
  }
  __syncthreads();

  const f32x4 z4 = {0.f, 0.f, 0.f, 0.f};
  f32x4 acc[4][4];
#pragma unroll
  for (int i = 0; i < 4; ++i)
#pragma unroll
    for (int j = 0; j < 4; ++j) acc[i][j] = z4;

  for (int k0 = 0; k0 < 1024; k0 += 32) {
#pragma unroll
    for (int it = 0; it < 2; ++it) {
      const int c = it * 4 + w;
      const int rr = c * 16 + l15;
      gl_lds16(Bt + (size_t)(n0 + rr) * 1024 + k0 + quad * 8, smem + 8192 + c * 1024);
    }
    // A: (Op0+Op1) * inv_l, staged manually with XOR-swizzled slots
    const int head = k0 >> 6;
#pragma unroll
    for (int it = 0; it < 2; ++it) {
      const int row = it * 64 + (t >> 2);
      const int aq = t & 3;
      const int slot = (row >> 4) * 64 + aq * 16 + ((row & 15) ^ (aq * 2));
      const size_t off = (size_t)(m0 + row) * 1024 + k0 + aq * 8;
      const h16x8 a0 = *(const h16x8*)(Op0 + off);
      const h16x8 a1 = *(const h16x8*)(Op1 + off);
      const float inv = inv_lds[row * 16 + head];
      h16x8 hv;
#pragma unroll
      for (int j = 0; j < 8; ++j)
        hv[j] = (_Float16)(((float)a0[j] + (float)a1[j]) * inv);
      lds8[slot] = hv;
    }
    __syncthreads();
    h16x8 af[4], bf[4];
#pragma unroll
    for (int i = 0; i < 4; ++i) {
      af[i] = lds8[(wm * 4 + i) * 64 + quad * 16 + (l15 ^ (quad * 2))];
      bf[i] = lds8[512 + (wn * 4 + i) * 64 + l];
    }
#pragma unroll
    for (int i = 0; i < 4; ++i)
#pragma unroll
      for (int j = 0; j < 4; ++j)
        acc[i][j] = __builtin_amdgcn_mfma_f32_16x16x32_f16(af[i], bf[j], acc[i][j], 0, 0, 0);
    __syncthreads();
  }
#pragma unroll
  for (int i = 0; i < 4; ++i)
#pragma unroll
    for (int j = 0; j < 4; ++j) {
      const int col = n0 + wn * 64 + j * 16 + l15;
      const float bv = bias[col];
#pragma unroll
      for (int r = 0; r < 4; ++r) {
        const int row = m0 + wm * 64 + i * 16 + quad * 4 + r;
        Cf[(size_t)row * 1024 + col] = fmaxf(acc[i][j][r] + bv, 0.f);
      }
    }
}

// ---------------------------------------------------------------------------
// Flash attention, split-K over 2 key halves (round-6 proven).
// 4 waves; 128 Q rows/block (32/wave, mi=2), 64-key tiles.
// Partials LINEAR (no softmax max): O_unnorm fp16 + l fp32.
// LDS: K[0,8K) V[8K,16K) P[16K,+8*2304) = 34816 B -> 4 blocks/CU.
// ---------------------------------------------------------------------------
__global__ __launch_bounds__(256, 4) void attn_k(
    const _Float16* __restrict__ Qf, const _Float16* __restrict__ Kf,
    const _Float16* __restrict__ Vtp,
    _Float16* __restrict__ Op0, _Float16* __restrict__ Op1,
    float* __restrict__ Lp) {
  __shared__ char smem[34816];
  h16x8* lds8 = (h16x8*)smem;
  const int t = threadIdx.x;
  const int l = t & 63, w = t >> 6;
  const int quad = l >> 4, l15 = l & 15;
  const int q0 = blockIdx.x * 128;
  const int bh = blockIdx.y;
  const int kz = blockIdx.z;
  const int b = bh >> 4, h = bh & 15;

  const _Float16* Kb = Kf + (size_t)bh * SEQ * 64;
  const _Float16* Vtb = Vtp + (size_t)bh * 64 * SEQ;

  h16x8 qf[2][2];
#pragma unroll
  for (int mi = 0; mi < 2; ++mi) {
    const size_t qb = ((size_t)bh * SEQ + q0 + w * 32 + mi * 16 + l15) * 64;
#pragma unroll
    for (int ks = 0; ks < 2; ++ks)
      qf[mi][ks] = *(const h16x8*)&Qf[qb + ks * 32 + quad * 8];
  }
  const f32x4 z4 = {0.f, 0.f, 0.f, 0.f};
  f32x4 oacc[2][4], lacc[2];
#pragma unroll
  for (int mi = 0; mi < 2; ++mi) {
    lacc[mi] = z4;
#pragma unroll
    for (int i = 0; i < 4; ++i) oacc[mi][i] = z4;
  }
  h16x8 ones;
#pragma unroll
  for (int j = 0; j < 8; ++j) ones[j] = (_Float16)1.0f;

  const int kbeg = kz * 1024;
  for (int k0 = kbeg; k0 < kbeg + 1024; k0 += 64) {
#pragma unroll
    for (int it = 0; it < 2; ++it) {
      const int c = it * 4 + w;
      const int kd = (c >> 1) * 16 + l15;
      const int off2 = (c & 1) * 32 + quad * 8;
      gl_lds16(Kb + (size_t)(k0 + kd) * 64 + off2, smem + c * 1024);
      gl_lds16(Vtb + (size_t)kd * SEQ + k0 + off2, smem + 8192 + c * 1024);
    }
    __syncthreads();

    {
      h16x8 kfr[4][2];
#pragma unroll
      for (int nt = 0; nt < 4; ++nt)
#pragma unroll
        for (int ks = 0; ks < 2; ++ks) kfr[nt][ks] = lds8[(nt * 2 + ks) * 64 + l];

#pragma unroll
      for (int mi = 0; mi < 2; ++mi) {
        f32x4 sacc[4];
#pragma unroll
        for (int nt = 0; nt < 4; ++nt) {
          f32x4 s = z4;
          s = __builtin_amdgcn_mfma_f32_16x16x32_f16(qf[mi][0], kfr[nt][0], s, 0, 0, 0);
          s = __builtin_amdgcn_mfma_f32_16x16x32_f16(qf[mi][1], kfr[nt][1], s, 0, 0, 0);
          sacc[nt] = s;
        }
        char* pb = smem + 16384 + (w * 2 + mi) * 2304;
#pragma unroll
        for (int r = 0; r < 4; ++r) {
          h16x4 pk;
#pragma unroll
          for (int nt = 0; nt < 4; ++nt)
            pk[nt] = (_Float16)__expf(sacc[nt][r] * 0.125f);
          *(h16x4*)(pb + (quad * 4 + r) * 144 + l15 * 8) = pk;
        }
      }
    }
    __asm__ __volatile__("" ::: "memory");  // same-wave DS ordering

    {
      h16x8 vfr[4][2];
#pragma unroll
      for (int nt = 0; nt < 4; ++nt)
#pragma unroll
        for (int ks = 0; ks < 2; ++ks) vfr[nt][ks] = lds8[512 + (nt * 2 + ks) * 64 + l];

#pragma unroll
      for (int mi = 0; mi < 2; ++mi) {
        char* pb = smem + 16384 + (w * 2 + mi) * 2304;
        const h16x8 pf0 = *(const h16x8*)(pb + l15 * 144 + quad * 16);
        const h16x8 pf1 = *(const h16x8*)(pb + l15 * 144 + 64 + quad * 16);
        lacc[mi] = __builtin_amdgcn_mfma_f32_16x16x32_f16(pf0, ones, lacc[mi], 0, 0, 0);
        lacc[mi] = __builtin_amdgcn_mfma_f32_16x16x32_f16(pf1, ones, lacc[mi], 0, 0, 0);
#pragma unroll
        for (int nt = 0; nt < 4; ++nt) {
          oacc[mi][nt] = __builtin_amdgcn_mfma_f32_16x16x32_f16(pf0, vfr[nt][0], oacc[mi][nt], 0, 0, 0);
          oacc[mi][nt] = __builtin_amdgcn_mfma_f32_16x16x32_f16(pf1, vfr[nt][1], oacc[mi][nt], 0, 0, 0);
        }
      }
    }
    __syncthreads();
  }

  _Float16* __restrict__ Op = kz ? Op1 : Op0;
#pragma unroll
  for (int mi = 0; mi < 2; ++mi)
#pragma unroll
    for (int nt = 0; nt < 4; ++nt)
#pragma unroll
      for (int r = 0; r < 4; ++r) {
        const size_t tok = (size_t)b * SEQ + q0 + w * 32 + mi * 16 + quad * 4 + r;
        Op[tok * 1024 + h * 64 + nt * 16 + l15] = (_Float16)oacc[mi][nt][r];
      }
  if (l15 == 0) {
#pragma unroll
    for (int mi = 0; mi < 2; ++mi)
#pragma unroll
      for (int r = 0; r < 4; ++r) {
        const int row = q0 + w * 32 + mi * 16 + quad * 4 + r;
        Lp[(size_t)kz * 65536 + bh * 2048 + row] = lacc[mi][r];
      }
  }
}

// ---------------------------------------------------------------------------
extern "C" void kernel_launch(void* const* d_in, const int* in_sizes, int n_in,
                              void* d_out, int out_size, void* d_ws, size_t ws_size,
                              hipStream_t stream) {
  const float* q = (const float*)d_in[0];
  const float* k = (const float*)d_in[1];
  const float* v = (const float*)d_in[2];
  const float* Wq = (const float*)d_in[3];
  const float* bq = (const float*)d_in[4];
  const float* Wk = (const float*)d_in[5];
  const float* bk = (const float*)d_in[6];
  const float* Wv = (const float*)d_in[7];
  const float* bv = (const float*)d_in[8];
  const float* Wo = (const float*)d_in[9];
  const float* bo = (const float*)d_in[10];

  char* W8 = (char*)d_ws;
  const size_t MB = 1024 * 1024;
  auto F = [&](size_t off) { return (_Float16*)(W8 + off); };
  // [0,8M): Wt f16 x4 | [8M,16M): qf (-> Op0) | [16M,24M): kf (-> Op1)
  // [24M,32M): vf | [32M,40M): Qf | [40M,48M): Kf | [48M,56M): Vb
  // [56M,64M): Vt | [64M,+512K): Lp                     (64.5 MB peak)
  _Float16* wt[4] = {F(0), F(2 * MB), F(4 * MB), F(6 * MB)};
  _Float16* qf = F(8 * MB);
  _Float16* kf = F(16 * MB);
  _Float16* vf = F(24 * MB);
  _Float16* Qf = F(32 * MB);
  _Float16* Kf = F(40 * MB);
  _Float16* Vb = F(48 * MB);
  _Float16* Vt = F(56 * MB);
  _Float16* Op0 = F(8 * MB);   // reuses qf (dead after gemm_qkv)
  _Float16* Op1 = F(16 * MB);  // reuses kf (dead after gemm_qkv)
  float* Lp = (float*)(W8 + 64 * MB);

  const dim3 blk(256);

  PrepArgs pa;
  pa.W[0] = Wq; pa.W[1] = Wk; pa.W[2] = Wv; pa.W[3] = Wo;
  pa.T[0] = wt[0]; pa.T[1] = wt[1]; pa.T[2] = wt[2]; pa.T[3] = wt[3];
  pa.X[0] = q; pa.X[1] = k; pa.X[2] = v;
  pa.H[0] = qf; pa.H[1] = kf; pa.H[2] = vf;
  prep_k<<<dim3(7168), blk, 0, stream>>>(pa);

  QKVArgs qa;
  qa.A[0] = qf; qa.A[1] = kf; qa.A[2] = vf;
  qa.Bt[0] = wt[0]; qa.Bt[1] = wt[1]; qa.Bt[2] = wt[2];
  qa.bias[0] = bq; qa.bias[1] = bk; qa.bias[2] = bv;
  qa.C[0] = Qf; qa.C[1] = Kf; qa.C[2] = Vb;
  gemm_qkv_k<<<dim3(8, 32, 3), blk, 0, stream>>>(qa);

  vtrans_k<<<dim3(32, 32), blk, 0, stream>>>((const unsigned short*)Vb,
                                             (unsigned short*)Vt);
  attn_k<<<dim3(16, 32, 2), blk, 0, stream>>>(Qf, Kf, Vt, Op0, Op1, Lp);
  gemm_o_k<<<dim3(8, 32), blk, 0, stream>>>(Op0, Op1, Lp, wt[3], bo, (float*)d_out);
}

// Round 9
// 255.483 us; speedup vs baseline: 1.0359x; 1.0221x over previous
//
#include <hip/hip_runtime.h>
#include <math.h>

#define SEQ 2048
#define NHD 16

typedef float f32x4 __attribute__((ext_vector_type(4), may_alias));
typedef _Float16 h16x8 __attribute__((ext_vector_type(8), may_alias));
typedef _Float16 h16x4 __attribute__((ext_vector_type(4), may_alias));

// async global->LDS, 16B per lane; dst wave-uniform base (+lane*16 in HW)
__device__ __forceinline__ void gl_lds16(const void* g, void* l) {
  __builtin_amdgcn_global_load_lds(
      (const __attribute__((address_space(1))) unsigned int*)g,
      (__attribute__((address_space(3))) unsigned int*)l, 16, 0, 0);
}

// ---------------------------------------------------------------------------
// Fused prepass: blocks [0,1024): transpose W{q,k,v,o} fp32->fp16 [n][k]
//                blocks [1024,7168): convert q,k,v fp32->fp16
// ---------------------------------------------------------------------------
struct PrepArgs {
  const float* W[4];
  _Float16* T[4];
  const float* X[3];
  _Float16* H[3];
};

__global__ __launch_bounds__(256) void prep_k(PrepArgs a) {
  __shared__ float tile[64][65];
  const int blk = blockIdx.x;
  const int t = threadIdx.x;
  if (blk < 1024) {
    const int widx = blk >> 8, tl = blk & 255;
    const int nb = (tl & 15) * 64, kb = (tl >> 4) * 64;
    const float* __restrict__ W = a.W[widx];
    _Float16* __restrict__ T = a.T[widx];
    const int c = t & 63, r0 = t >> 6;
#pragma unroll
    for (int i = 0; i < 16; ++i) {
      const int r = i * 4 + r0;
      tile[r][c] = W[(size_t)(kb + r) * 1024 + nb + c];
    }
    __syncthreads();
#pragma unroll
    for (int i = 0; i < 16; ++i) {
      const int n = i * 4 + r0;
      T[(size_t)(nb + n) * 1024 + kb + c] = (_Float16)tile[c][n];
    }
  } else {
    const int b2 = blk - 1024;
    const int z = b2 >> 11, bx = b2 & 2047;
    const float* __restrict__ X = a.X[z];
    _Float16* __restrict__ H = a.H[z];
    const size_t i = ((size_t)bx * 256 + t) * 8;
    const f32x4 f0 = *(const f32x4*)(X + i);
    const f32x4 f1 = *(const f32x4*)(X + i + 4);
    const float fs[8] = {f0.x, f0.y, f0.z, f0.w, f1.x, f1.y, f1.z, f1.w};
    h16x8 o;
#pragma unroll
    for (int j = 0; j < 8; ++j) o[j] = (_Float16)fs[j];
    *(h16x8*)(H + i) = o;
  }
}

// ---------------------------------------------------------------------------
// V transpose + key'-permute (fp16 bits as u16): Vb[bh][s][64] -> Vt[bh][64][2048]
// key' = (key&15)*4 + (key>>4) within each 64-key block
// ---------------------------------------------------------------------------
__global__ __launch_bounds__(256) void vtrans_k(const unsigned short* __restrict__ Vb,
                                                unsigned short* __restrict__ Vt) {
  __shared__ unsigned short tile[64][65];
  const int t = threadIdx.x;
  const int c = t & 63, r0 = t >> 6;
  const int s0 = blockIdx.x * 64;
  const int bh = blockIdx.y;
#pragma unroll
  for (int i = 0; i < 16; ++i) {
    const int r = i * 4 + r0;
    tile[r][c] = Vb[((size_t)bh * SEQ + s0 + r) * 64 + c];
  }
  __syncthreads();
#pragma unroll
  for (int i = 0; i < 16; ++i) {
    const int d = i * 4 + r0;
    const int sp = ((c & 15) * 4) + (c >> 4);
    Vt[((size_t)bh * 64 + d) * SEQ + s0 + sp] = tile[c][d];
  }
}

// ---------------------------------------------------------------------------
// fp16 MFMA GEMM: C = A[M x 1024] @ Bt^T + bias, head-split fp16 output.
// Tile 128x128, BK=32, 4 waves (2x2), 4x4 16x16 tiles/wave, 16 MFMA/k-step.
// LDS: A[0,8K) B[8K,16K), staged via global_load_lds dwordx4 in frag order.
// 1D grid + XCD swizzle: blocks sharing an A m-tile (all 8 n-tiles) are
// congruent mod 8 -> same XCD -> A k-slices hit that XCD's L2 7/8 times.
// ---------------------------------------------------------------------------
struct QKVArgs {
  const _Float16* A[3];
  const _Float16* Bt[3];
  const float* bias[3];
  _Float16* C[3];
};

__global__ __launch_bounds__(256, 4) void gemm_qkv_k(QKVArgs a) {
  __shared__ char smem[16384];
  h16x8* lds8 = (h16x8*)smem;
  const int dblk = blockIdx.x;
  const int z = dblk >> 8;
  const int rb = dblk & 255;
  // XCD swizzle: xcd = rb&7; m-group = rb>>6; x = (rb>>3)&7
  const int n0 = ((rb >> 3) & 7) * 128;
  const int m0 = ((((rb >> 6) << 3) | (rb & 7))) * 128;
  const _Float16* __restrict__ A = a.A[z];
  const _Float16* __restrict__ Bt = a.Bt[z];
  const float* __restrict__ bias = a.bias[z];
  _Float16* __restrict__ C = a.C[z];

  const int t = threadIdx.x;
  const int l = t & 63, w = t >> 6;
  const int quad = l >> 4, l15 = l & 15;
  const int wm = w >> 1, wn = w & 1;

  const f32x4 z4 = {0.f, 0.f, 0.f, 0.f};
  f32x4 acc[4][4];
#pragma unroll
  for (int i = 0; i < 4; ++i)
#pragma unroll
    for (int j = 0; j < 4; ++j) acc[i][j] = z4;

  for (int k0 = 0; k0 < 1024; k0 += 32) {
#pragma unroll
    for (int it = 0; it < 2; ++it) {
      const int c = it * 4 + w;
      const int rr = c * 16 + l15;
      gl_lds16(A + (size_t)(m0 + rr) * 1024 + k0 + quad * 8, smem + c * 1024);
      gl_lds16(Bt + (size_t)(n0 + rr) * 1024 + k0 + quad * 8, smem + 8192 + c * 1024);
    }
    __syncthreads();
    h16x8 af[4], bf[4];
#pragma unroll
    for (int i = 0; i < 4; ++i) {
      af[i] = lds8[(wm * 4 + i) * 64 + l];
      bf[i] = lds8[512 + (wn * 4 + i) * 64 + l];
    }
#pragma unroll
    for (int i = 0; i < 4; ++i)
#pragma unroll
      for (int j = 0; j < 4; ++j)
        acc[i][j] = __builtin_amdgcn_mfma_f32_16x16x32_f16(af[i], bf[j], acc[i][j], 0, 0, 0);
    __syncthreads();
  }
#pragma unroll
  for (int i = 0; i < 4; ++i)
#pragma unroll
    for (int j = 0; j < 4; ++j) {
      const int col = n0 + wn * 64 + j * 16 + l15;
      const float bv = bias[col];
#pragma unroll
      for (int r = 0; r < 4; ++r) {
        const int row = m0 + wm * 64 + i * 16 + quad * 4 + r;
        const int b = row >> 11, s = row & 2047;
        const int h = col >> 6, d = col & 63;
        C[((size_t)(b * NHD + h) * SEQ + s) * 64 + d] = (_Float16)(acc[i][j][r] + bv);
      }
    }
}

// ---------------------------------------------------------------------------
// Output GEMM with fused split-K combine + normalization:
//   Cf = relu( [ (Op0+Op1) * inv_l(token,head) ] @ Wo_t^T + bias )
// inv_l applied during A-staging (head = k0>>6 wave-uniform); per-block LDS
// table 1/(l0+l1). A slots XOR-swizzled ((row&15)^(2*aq)) -> <=2-way (free).
// 1D grid + XCD swizzle (same scheme as gemm_qkv).
// LDS: A[0,8K) B[8K,16K) inv[16K,24K).
// ---------------------------------------------------------------------------
__global__ __launch_bounds__(256, 4) void gemm_o_k(
    const _Float16* __restrict__ Op0, const _Float16* __restrict__ Op1,
    const float* __restrict__ Lp, const _Float16* __restrict__ Bt,
    const float* __restrict__ bias, float* __restrict__ Cf) {
  __shared__ char smem[24576];
  h16x8* lds8 = (h16x8*)smem;
  float* inv_lds = (float*)(smem + 16384);  // [row_local][head]
  const int rb = blockIdx.x;  // 256 blocks
  const int n0 = ((rb >> 3) & 7) * 128;
  const int m0 = ((((rb >> 6) << 3) | (rb & 7))) * 128;
  const int t = threadIdx.x;
  const int l = t & 63, w = t >> 6;
  const int quad = l >> 4, l15 = l & 15;
  const int wm = w >> 1, wn = w & 1;

  // precompute inv_l for this block's 128 rows x 16 heads
#pragma unroll
  for (int e = t; e < 2048; e += 256) {
    const int rl = e >> 4, hh = e & 15;
    const int m = m0 + rl;
    const int b = m >> 11, s = m & 2047;
    const size_t li = (size_t)(b * NHD + hh) * 2048 + s;
    inv_lds[e] = 1.f / (Lp[li] + Lp[65536 + li]);
  }
  __syncthreads();

  const f32x4 z4 = {0.f, 0.f, 0.f, 0.f};
  f32x4 acc[4][4];
#pragma unroll
  for (int i = 0; i < 4; ++i)
#pragma unroll
    for (int j = 0; j < 4; ++j) acc[i][j] = z4;

  for (int k0 = 0; k0 < 1024; k0 += 32) {
#pragma unroll
    for (int it = 0; it < 2; ++it) {
      const int c = it * 4 + w;
      const int rr = c * 16 + l15;
      gl_lds16(Bt + (size_t)(n0 + rr) * 1024 + k0 + quad * 8, smem + 8192 + c * 1024);
    }
    // A: (Op0+Op1) * inv_l, staged manually with XOR-swizzled slots
    const int head = k0 >> 6;
#pragma unroll
    for (int it = 0; it < 2; ++it) {
      const int row = it * 64 + (t >> 2);
      const int aq = t & 3;
      const int slot = (row >> 4) * 64 + aq * 16 + ((row & 15) ^ (aq * 2));
      const size_t off = (size_t)(m0 + row) * 1024 + k0 + aq * 8;
      const h16x8 a0 = *(const h16x8*)(Op0 + off);
      const h16x8 a1 = *(const h16x8*)(Op1 + off);
      const float inv = inv_lds[row * 16 + head];
      h16x8 hv;
#pragma unroll
      for (int j = 0; j < 8; ++j)
        hv[j] = (_Float16)(((float)a0[j] + (float)a1[j]) * inv);
      lds8[slot] = hv;
    }
    __syncthreads();
    h16x8 af[4], bf[4];
#pragma unroll
    for (int i = 0; i < 4; ++i) {
      af[i] = lds8[(wm * 4 + i) * 64 + quad * 16 + (l15 ^ (quad * 2))];
      bf[i] = lds8[512 + (wn * 4 + i) * 64 + l];
    }
#pragma unroll
    for (int i = 0; i < 4; ++i)
#pragma unroll
      for (int j = 0; j < 4; ++j)
        acc[i][j] = __builtin_amdgcn_mfma_f32_16x16x32_f16(af[i], bf[j], acc[i][j], 0, 0, 0);
    __syncthreads();
  }
#pragma unroll
  for (int i = 0; i < 4; ++i)
#pragma unroll
    for (int j = 0; j < 4; ++j) {
      const int col = n0 + wn * 64 + j * 16 + l15;
      const float bv = bias[col];
#pragma unroll
      for (int r = 0; r < 4; ++r) {
        const int row = m0 + wm * 64 + i * 16 + quad * 4 + r;
        Cf[(size_t)row * 1024 + col] = fmaxf(acc[i][j][r] + bv, 0.f);
      }
    }
}

// ---------------------------------------------------------------------------
// Flash attention, split-K over 2 key halves. 4 waves; 128 Q rows/block
// (32/wave, mi=2), 64-key tiles. Partials LINEAR: O_unnorm fp16 + l fp32.
// 1D grid + XCD swizzle: the 16 q-tile blocks of one (bh,kz) are congruent
// mod 8 -> same XCD -> its K/V half (256 KB) stays L2-resident.
// LDS: K[0,8K) V[8K,16K) P[16K,+8*2304) = 34816 B -> 4 blocks/CU.
// ---------------------------------------------------------------------------
__global__ __launch_bounds__(256, 4) void attn_k(
    const _Float16* __restrict__ Qf, const _Float16* __restrict__ Kf,
    const _Float16* __restrict__ Vtp,
    _Float16* __restrict__ Op0, _Float16* __restrict__ Op1,
    float* __restrict__ Lp) {
  __shared__ char smem[34816];
  h16x8* lds8 = (h16x8*)smem;
  const int dblk = blockIdx.x;  // 1024 blocks
  const int comb = ((dblk >> 7) << 3) | (dblk & 7);  // (bh,kz) combo, [0,64)
  const int q0 = ((dblk >> 3) & 15) * 128;
  const int bh = comb >> 1;
  const int kz = comb & 1;
  const int t = threadIdx.x;
  const int l = t & 63, w = t >> 6;
  const int quad = l >> 4, l15 = l & 15;
  const int b = bh >> 4, h = bh & 15;

  const _Float16* Kb = Kf + (size_t)bh * SEQ * 64;
  const _Float16* Vtb = Vtp + (size_t)bh * 64 * SEQ;

  h16x8 qf[2][2];
#pragma unroll
  for (int mi = 0; mi < 2; ++mi) {
    const size_t qb = ((size_t)bh * SEQ + q0 + w * 32 + mi * 16 + l15) * 64;
#pragma unroll
    for (int ks = 0; ks < 2; ++ks)
      qf[mi][ks] = *(const h16x8*)&Qf[qb + ks * 32 + quad * 8];
  }
  const f32x4 z4 = {0.f, 0.f, 0.f, 0.f};
  f32x4 oacc[2][4], lacc[2];
#pragma unroll
  for (int mi = 0; mi < 2; ++mi) {
    lacc[mi] = z4;
#pragma unroll
    for (int i = 0; i < 4; ++i) oacc[mi][i] = z4;
  }
  h16x8 ones;
#pragma unroll
  for (int j = 0; j < 8; ++j) ones[j] = (_Float16)1.0f;

  const int kbeg = kz * 1024;
  for (int k0 = kbeg; k0 < kbeg + 1024; k0 += 64) {
#pragma unroll
    for (int it = 0; it < 2; ++it) {
      const int c = it * 4 + w;
      const int kd = (c >> 1) * 16 + l15;
      const int off2 = (c & 1) * 32 + quad * 8;
      gl_lds16(Kb + (size_t)(k0 + kd) * 64 + off2, smem + c * 1024);
      gl_lds16(Vtb + (size_t)kd * SEQ + k0 + off2, smem + 8192 + c * 1024);
    }
    __syncthreads();

    {
      h16x8 kfr[4][2];
#pragma unroll
      for (int nt = 0; nt < 4; ++nt)
#pragma unroll
        for (int ks = 0; ks < 2; ++ks) kfr[nt][ks] = lds8[(nt * 2 + ks) * 64 + l];

#pragma unroll
      for (int mi = 0; mi < 2; ++mi) {
        f32x4 sacc[4];
#pragma unroll
        for (int nt = 0; nt < 4; ++nt) {
          f32x4 s = z4;
          s = __builtin_amdgcn_mfma_f32_16x16x32_f16(qf[mi][0], kfr[nt][0], s, 0, 0, 0);
          s = __builtin_amdgcn_mfma_f32_16x16x32_f16(qf[mi][1], kfr[nt][1], s, 0, 0, 0);
          sacc[nt] = s;
        }
        char* pb = smem + 16384 + (w * 2 + mi) * 2304;
#pragma unroll
        for (int r = 0; r < 4; ++r) {
          h16x4 pk;
#pragma unroll
          for (int nt = 0; nt < 4; ++nt)
            pk[nt] = (_Float16)__expf(sacc[nt][r] * 0.125f);
          *(h16x4*)(pb + (quad * 4 + r) * 144 + l15 * 8) = pk;
        }
      }
    }
    __asm__ __volatile__("" ::: "memory");  // same-wave DS ordering

    {
      h16x8 vfr[4][2];
#pragma unroll
      for (int nt = 0; nt < 4; ++nt)
#pragma unroll
        for (int ks = 0; ks < 2; ++ks) vfr[nt][ks] = lds8[512 + (nt * 2 + ks) * 64 + l];

#pragma unroll
      for (int mi = 0; mi < 2; ++mi) {
        char* pb = smem + 16384 + (w * 2 + mi) * 2304;
        const h16x8 pf0 = *(const h16x8*)(pb + l15 * 144 + quad * 16);
        const h16x8 pf1 = *(const h16x8*)(pb + l15 * 144 + 64 + quad * 16);
        lacc[mi] = __builtin_amdgcn_mfma_f32_16x16x32_f16(pf0, ones, lacc[mi], 0, 0, 0);
        lacc[mi] = __builtin_amdgcn_mfma_f32_16x16x32_f16(pf1, ones, lacc[mi], 0, 0, 0);
#pragma unroll
        for (int nt = 0; nt < 4; ++nt) {
          oacc[mi][nt] = __builtin_amdgcn_mfma_f32_16x16x32_f16(pf0, vfr[nt][0], oacc[mi][nt], 0, 0, 0);
          oacc[mi][nt] = __builtin_amdgcn_mfma_f32_16x16x32_f16(pf1, vfr[nt][1], oacc[mi][nt], 0, 0, 0);
        }
      }
    }
    __syncthreads();
  }

  _Float16* __restrict__ Op = kz ? Op1 : Op0;
#pragma unroll
  for (int mi = 0; mi < 2; ++mi)
#pragma unroll
    for (int nt = 0; nt < 4; ++nt)
#pragma unroll
      for (int r = 0; r < 4; ++r) {
        const size_t tok = (size_t)b * SEQ + q0 + w * 32 + mi * 16 + quad * 4 + r;
        Op[tok * 1024 + h * 64 + nt * 16 + l15] = (_Float16)oacc[mi][nt][r];
      }
  if (l15 == 0) {
#pragma unroll
    for (int mi = 0; mi < 2; ++mi)
#pragma unroll
      for (int r = 0; r < 4; ++r) {
        const int row = q0 + w * 32 + mi * 16 + quad * 4 + r;
        Lp[(size_t)kz * 65536 + bh * 2048 + row] = lacc[mi][r];
      }
  }
}

// ---------------------------------------------------------------------------
extern "C" void kernel_launch(void* const* d_in, const int* in_sizes, int n_in,
                              void* d_out, int out_size, void* d_ws, size_t ws_size,
                              hipStream_t stream) {
  const float* q = (const float*)d_in[0];
  const float* k = (const float*)d_in[1];
  const float* v = (const float*)d_in[2];
  const float* Wq = (const float*)d_in[3];
  const float* bq = (const float*)d_in[4];
  const float* Wk = (const float*)d_in[5];
  const float* bk = (const float*)d_in[6];
  const float* Wv = (const float*)d_in[7];
  const float* bv = (const float*)d_in[8];
  const float* Wo = (const float*)d_in[9];
  const float* bo = (const float*)d_in[10];

  char* W8 = (char*)d_ws;
  const size_t MB = 1024 * 1024;
  auto F = [&](size_t off) { return (_Float16*)(W8 + off); };
  // [0,8M): Wt f16 x4 | [8M,16M): qf (-> Op0) | [16M,24M): kf (-> Op1)
  // [24M,32M): vf | [32M,40M): Qf | [40M,48M): Kf | [48M,56M): Vb
  // [56M,64M): Vt | [64M,+512K): Lp                     (64.5 MB peak)
  _Float16* wt[4] = {F(0), F(2 * MB), F(4 * MB), F(6 * MB)};
  _Float16* qf = F(8 * MB);
  _Float16* kf = F(16 * MB);
  _Float16* vf = F(24 * MB);
  _Float16* Qf = F(32 * MB);
  _Float16* Kf = F(40 * MB);
  _Float16* Vb = F(48 * MB);
  _Float16* Vt = F(56 * MB);
  _Float16* Op0 = F(8 * MB);   // reuses qf (dead after gemm_qkv)
  _Float16* Op1 = F(16 * MB);  // reuses kf (dead after gemm_qkv)
  float* Lp = (float*)(W8 + 64 * MB);

  const dim3 blk(256);

  PrepArgs pa;
  pa.W[0] = Wq; pa.W[1] = Wk; pa.W[2] = Wv; pa.W[3] = Wo;
  pa.T[0] = wt[0]; pa.T[1] = wt[1]; pa.T[2] = wt[2]; pa.T[3] = wt[3];
  pa.X[0] = q; pa.X[1] = k; pa.X[2] = v;
  pa.H[0] = qf; pa.H[1] = kf; pa.H[2] = vf;
  prep_k<<<dim3(7168), blk, 0, stream>>>(pa);

  QKVArgs qa;
  qa.A[0] = qf; qa.A[1] = kf; qa.A[2] = vf;
  qa.Bt[0] = wt[0]; qa.Bt[1] = wt[1]; qa.Bt[2] = wt[2];
  qa.bias[0] = bq; qa.bias[1] = bk; qa.bias[2] = bv;
  qa.C[0] = Qf; qa.C[1] = Kf; qa.C[2] = Vb;
  gemm_qkv_k<<<dim3(768), blk, 0, stream>>>(qa);

  vtrans_k<<<dim3(32, 32), blk, 0, stream>>>((const unsigned short*)Vb,
                                             (unsigned short*)Vt);
  attn_k<<<dim3(1024), blk, 0, stream>>>(Qf, Kf, Vt, Op0, Op1, Lp);
  gemm_o_k<<<dim3(256), blk, 0, stream>>>(Op0, Op1, Lp, wt[3], bo, (float*)d_out);
}